// Round 19
// baseline (107.394 us; speedup 1.0000x reference)
//
#include <hip/hip_runtime.h>
#include <hip/hip_bf16.h>

#define BATCH 4
#define NQ 1024
#define NKK 1024
#define HD 1024
#define NHEADS 16

typedef __bf16 bf16x8 __attribute__((ext_vector_type(8)));
typedef float f32x4 __attribute__((ext_vector_type(4)));
typedef unsigned short u16;
typedef unsigned short u16x8 __attribute__((ext_vector_type(8)));
typedef unsigned int u32;

__device__ __forceinline__ u16 f2bf(float f) {
    union { __bf16 h; u16 u; } v;
    v.h = (__bf16)f;
    return v.u;
}

#define GLOAD16(gp, lp) \
    __builtin_amdgcn_global_load_lds((const __attribute__((address_space(1))) void*)(gp), \
                                     (__attribute__((address_space(3))) void*)(lp), 16, 0, 0)

#define MFMA16(a, b, c) __builtin_amdgcn_mfma_f32_16x16x32_bf16(a, b, c, 0, 0, 0)

#define SBAR()  do { __builtin_amdgcn_sched_barrier(0); __builtin_amdgcn_s_barrier(); \
                     __builtin_amdgcn_sched_barrier(0); } while (0)
#define VMW(N)  do { asm volatile("s_waitcnt vmcnt(" #N ")" ::: "memory"); \
                     __builtin_amdgcn_sched_barrier(0); } while (0)

// ---------------------------------------------------------------------------
// Merged preprocessing, one launch. grid (16,16,6), block 256.
__global__ __launch_bounds__(256) void prep_k(const float* __restrict__ x,
                                              const float* __restrict__ ctx,
                                              const float* __restrict__ w0,
                                              const float* __restrict__ w1,
                                              const float* __restrict__ w2,
                                              const float* __restrict__ w3,
                                              u16* __restrict__ ws,
                                              u16* __restrict__ Xb,
                                              u16* __restrict__ Cb) {
    const int tid = threadIdx.x;
    const int z = blockIdx.z;
    if (z >= 4) {
        const float* src = (z == 4) ? x : ctx;
        u16* dst = (z == 4) ? Xb : Cb;
        const int seg = blockIdx.y * 16 + blockIdx.x;
#pragma unroll
        for (int p = 0; p < 16; ++p) {
            const int i = seg * 4096 + p * 256 + tid;
            float4 v = ((const float4*)src)[i];
            ushort4 pk;
            pk.x = f2bf(v.x); pk.y = f2bf(v.y); pk.z = f2bf(v.z); pk.w = f2bf(v.w);
            ((ushort4*)dst)[i] = pk;
        }
        return;
    }
    const float* src = z == 0 ? w0 : z == 1 ? w1 : z == 2 ? w2 : w3;
    const float scl = (z == 0) ? 0.18033688011112042f : 1.0f;  // 0.125*log2e
    u16* dst = ws + (size_t)z * (1024u * 1024u);
    __shared__ u16 t[64][65];
    const int bx = blockIdx.x * 64;
    const int by = blockIdx.y * 64;
#pragma unroll
    for (int p = 0; p < 16; ++p) {
        int idx = p * 256 + tid;
        int r = idx >> 6, c = idx & 63;
        t[c][r] = f2bf(scl * src[(size_t)(by + r) * 1024 + bx + c]);
    }
    __syncthreads();
#pragma unroll
    for (int p = 0; p < 16; ++p) {
        int idx = p * 256 + tid;
        int r = idx >> 6, c = idx & 63;
        dst[(size_t)(bx + r) * 1024 + by + c] = t[r][c];
    }
}

// ---------------------------------------------------------------------------
// 8-phase 256x256 fused QKV GEMM.  C[4096][3072] over BT3=[WqT|WkT|WvT].
// BK=64, 8 waves (512 thr), wave = 128x64 (acc[8][4]).  Double-buffered
// 128KB dynamic LDS, chunk-XOR swizzle (chunk c of row r at c^(r&7); gload
// source inverse-permuted).  Counted vmcnt(4) only at phases 4/8; staging is
// half-tile (128-row) granular, ordered so each region is overwritten only
// after the barrier following its last reader.  grid 192 (8 XCD x 24).
template <int TB, int MH, int NH, class F>
__device__ __forceinline__ void phase8(const u16* Asm, const u16* Bsm,
                                       int wm, int wn, int lr, int lg, int lx,
                                       f32x4 (&acc)[8][4], F&& stage) {
    const u16* As = Asm + TB * 16384;
    const u16* Bs = Bsm + TB * 16384;
    bf16x8 af[4][2], bfr[2][2];
#pragma unroll
    for (int m = 0; m < 4; ++m)
#pragma unroll
        for (int kk = 0; kk < 2; ++kk)
            af[m][kk] = *(const bf16x8*)&As[((wm * 128 + MH * 64 + m * 16 + lr) * 8 +
                                            ((kk * 4 + lg) ^ lx)) * 8];
#pragma unroll
    for (int n = 0; n < 2; ++n)
#pragma unroll
        for (int kk = 0; kk < 2; ++kk)
            bfr[n][kk] = *(const bf16x8*)&Bs[((wn * 64 + NH * 32 + n * 16 + lr) * 8 +
                                             ((kk * 4 + lg) ^ lx)) * 8];
    stage();
    SBAR();                                   // phase barrier #1
    __builtin_amdgcn_s_setprio(1);
#pragma unroll
    for (int kk = 0; kk < 2; ++kk)
#pragma unroll
        for (int m = 0; m < 4; ++m)
#pragma unroll
            for (int n = 0; n < 2; ++n)
                acc[MH * 4 + m][NH * 2 + n] =
                    MFMA16(af[m][kk], bfr[n][kk], acc[MH * 4 + m][NH * 2 + n]);
    __builtin_amdgcn_s_setprio(0);
    __builtin_amdgcn_sched_barrier(0);
}

__global__ __launch_bounds__(512, 2) void gemm_qkv8(const u16* __restrict__ Xb,
                                                    const u16* __restrict__ Cb,
                                                    const u16* __restrict__ BT3,
                                                    u16* __restrict__ Qb,
                                                    u16* __restrict__ Kb,
                                                    u16* __restrict__ VTb) {
    extern __shared__ __align__(16) u16 dynlds[];
    u16* Asm = dynlds;                 // [2][256*64]
    u16* Bsm = dynlds + 2 * 16384;     // [2][256*64]

    const int bid = blockIdx.x;
    const int swz = (bid & 7) * 24 + (bid >> 3);    // bijective on [0,192)
    const int m0 = (swz / 12) * 256;                // <= 3840
    const int nblk = swz % 12;
    const int n0g = nblk * 256;                     // [0,3072)
    const int z = n0g >> 10;
    const int nc0 = n0g & 1023;

    const u16* __restrict__ A = (z == 0) ? Xb : Cb;

    const int tid = threadIdx.x, lane = tid & 63, wv = tid >> 6;
    const int wm = wv >> 2, wn = wv & 3;    // 2 x 4 waves; wave = 128 rows x 64 cols
    const int lr = lane & 15, lg = lane >> 4;
    const int lx = lr & 7;
    const int M = BATCH * NQ;

    // region staging: half = 128 rows, 2 gloads/thread
    auto stageA = [&](int T, int half) {
        const int tb = T & 1;
        const int kt = T * 64;
#pragma unroll
        for (int j = 0; j < 2; ++j) {
            const int s = j * 512 + tid;
            const int rp = s >> 3, pc = s & 7;
            const int r = rp + (rp & 64) + half * 64;     // {0-63,128-191} (+64)
            const int cg = pc ^ (r & 7);
            GLOAD16(A + (size_t)(m0 + r) * 1024 + kt + cg * 8,
                    Asm + tb * 16384 + (r * 8 + pc) * 8);
        }
    };
    auto stageB = [&](int T, int half) {
        const int tb = T & 1;
        const int kt = T * 64;
#pragma unroll
        for (int j = 0; j < 2; ++j) {
            const int s = j * 512 + tid;
            const int rp = s >> 3, pc = s & 7;
            const int r = (rp & 31) + ((rp >> 5) << 6) + half * 32;  // n-half rows
            const int cg = pc ^ (r & 7);
            GLOAD16(BT3 + (size_t)(n0g + r) * 1024 + kt + cg * 8,
                    Bsm + tb * 16384 + (r * 8 + pc) * 8);
        }
    };

    f32x4 acc[8][4];
#pragma unroll
    for (int i = 0; i < 8; ++i)
#pragma unroll
        for (int j = 0; j < 4; ++j) acc[i][j] = (f32x4)(0.0f);

    // prologue: tiles 0 and 1 fully staged (16 loads/thread)
    stageA(0, 0); stageA(0, 1); stageB(0, 0); stageB(0, 1);
    stageA(1, 0); stageA(1, 1); stageB(1, 0); stageB(1, 1);
    VMW(8);                       // tile 0 landed (own loads) ...
    SBAR();                       // ... on all threads

    for (int i = 0; i < 7; ++i) {
        const int t1 = 2 * i + 1, t2 = 2 * i + 2, t3 = 2 * i + 3;
        phase8<0, 0, 0>(Asm, Bsm, wm, wn, lr, lg, lx, acc,
                        [&] { if (i) stageA(t1, 1); });
        SBAR();
        phase8<0, 0, 1>(Asm, Bsm, wm, wn, lr, lg, lx, acc,
                        [&] { if (i) stageB(t1, 1); });
        SBAR();
        phase8<0, 1, 0>(Asm, Bsm, wm, wn, lr, lg, lx, acc, [&] { stageA(t2, 0); });
        SBAR();
        phase8<0, 1, 1>(Asm, Bsm, wm, wn, lr, lg, lx, acc, [&] { stageB(t2, 0); });
        VMW(4); SBAR();           // tile 2i+1 fully resident
        phase8<1, 0, 0>(Asm, Bsm, wm, wn, lr, lg, lx, acc, [&] { stageA(t2, 1); });
        SBAR();
        phase8<1, 0, 1>(Asm, Bsm, wm, wn, lr, lg, lx, acc, [&] { stageB(t2, 1); });
        SBAR();
        phase8<1, 1, 0>(Asm, Bsm, wm, wn, lr, lg, lx, acc, [&] { stageA(t3, 0); });
        SBAR();
        phase8<1, 1, 1>(Asm, Bsm, wm, wn, lr, lg, lx, acc, [&] { stageB(t3, 0); });
        VMW(4); SBAR();           // tile 2i+2 fully resident
    }
    // iteration 7: tiles 14 (buf0), 15 (buf1); finish staging tile 15, then drain
    phase8<0, 0, 0>(Asm, Bsm, wm, wn, lr, lg, lx, acc, [&] { stageA(15, 1); });
    SBAR();
    phase8<0, 0, 1>(Asm, Bsm, wm, wn, lr, lg, lx, acc, [&] { stageB(15, 1); });
    SBAR();
    phase8<0, 1, 0>(Asm, Bsm, wm, wn, lr, lg, lx, acc, [&] {});
    SBAR();
    phase8<0, 1, 1>(Asm, Bsm, wm, wn, lr, lg, lx, acc, [&] {});
    VMW(0); SBAR();
    phase8<1, 0, 0>(Asm, Bsm, wm, wn, lr, lg, lx, acc, [&] {});
    SBAR();
    phase8<1, 0, 1>(Asm, Bsm, wm, wn, lr, lg, lx, acc, [&] {});
    SBAR();
    phase8<1, 1, 0>(Asm, Bsm, wm, wn, lr, lg, lx, acc, [&] {});
    SBAR();
    phase8<1, 1, 1>(Asm, Bsm, wm, wn, lr, lg, lx, acc, [&] {});

    if (z < 2) {
        u16* __restrict__ C = (z == 0) ? Qb : Kb;
#pragma unroll
        for (int mf = 0; mf < 8; ++mf)
#pragma unroll
            for (int nf = 0; nf < 4; ++nf) {
                const int col = nc0 + wn * 64 + nf * 16 + lr;
                const int rb = m0 + wm * 128 + mf * 16 + lg * 4;
#pragma unroll
                for (int r = 0; r < 4; ++r)
                    C[(size_t)(rb + r) * HD + col] = f2bf(acc[mf][nf][r]);
            }
    } else {
#pragma unroll
        for (int mf = 0; mf < 8; ++mf)
#pragma unroll
            for (int nf = 0; nf < 4; ++nf) {
                const int col = nc0 + wn * 64 + nf * 16 + lr;
                const int rb = m0 + wm * 128 + mf * 16 + lg * 4;
                ushort4 pk;
                pk.x = f2bf(acc[mf][nf][0]);
                pk.y = f2bf(acc[mf][nf][1]);
                pk.z = f2bf(acc[mf][nf][2]);
                pk.w = f2bf(acc[mf][nf][3]);
                *(ushort4*)&VTb[(size_t)col * M + rb] = pk;
            }
    }
}

// ---------------------------------------------------------------------------
// Output projection with f32 bias: out = AO @ Wo + bo -> f32.
// 128x128 tiles, 8 waves, BK=64, swizzled LDS. grid 256 (= 8 XCD x 32).
__global__ __launch_bounds__(512) void gemm_out(const u16* __restrict__ A,
                                                const u16* __restrict__ BT,
                                                const float* __restrict__ bias,
                                                float* __restrict__ C) {
    const int bid = blockIdx.x;
    const int swz = (bid & 7) * 32 + (bid >> 3);
    const int m0 = (swz >> 3) * 128;
    const int n0 = (swz & 7) * 128;

    __shared__ __align__(16) u16 Asm[128 * 64];
    __shared__ __align__(16) u16 Bsm[128 * 64];

    const int tid = threadIdx.x, lane = tid & 63, wv = tid >> 6;
    const int wm = wv >> 2, wn = wv & 3;
    const int lr = lane & 15, lg = lane >> 4;
    const int lx = lr & 7;
    const int N = HD, K = HD;

    f32x4 acc[4][2];
#pragma unroll
    for (int i = 0; i < 4; ++i)
#pragma unroll
        for (int j = 0; j < 2; ++j) acc[i][j] = (f32x4)(0.0f);

    for (int kt = 0; kt < K; kt += 64) {
        __syncthreads();
#pragma unroll
        for (int i = 0; i < 2; ++i) {
            const int cb = (wv * 2 + i) * 64;
            const int s = cb + lane;
            const int row = s >> 3, cg = (s & 7) ^ (row & 7);
            GLOAD16(A + (size_t)(m0 + row) * K + kt + cg * 8, &Asm[cb * 8]);
            GLOAD16(BT + (size_t)(n0 + row) * K + kt + cg * 8, &Bsm[cb * 8]);
        }
        __syncthreads();
        bf16x8 af[4][2], bfr[2][2];
#pragma unroll
        for (int m = 0; m < 4; ++m)
#pragma unroll
            for (int kk = 0; kk < 2; ++kk)
                af[m][kk] = *(const bf16x8*)&Asm[((wm * 64 + m * 16 + lr) * 8 +
                                                 ((kk * 4 + lg) ^ lx)) * 8];
#pragma unroll
        for (int n = 0; n < 2; ++n)
#pragma unroll
            for (int kk = 0; kk < 2; ++kk)
                bfr[n][kk] = *(const bf16x8*)&Bsm[((wn * 32 + n * 16 + lr) * 8 +
                                                  ((kk * 4 + lg) ^ lx)) * 8];
#pragma unroll
        for (int kk = 0; kk < 2; ++kk)
#pragma unroll
            for (int m = 0; m < 4; ++m)
#pragma unroll
                for (int n = 0; n < 2; ++n)
                    acc[m][n] = MFMA16(af[m][kk], bfr[n][kk], acc[m][n]);
    }

#pragma unroll
    for (int m = 0; m < 4; ++m)
#pragma unroll
        for (int n = 0; n < 2; ++n) {
            const int col = n0 + wn * 32 + n * 16 + lr;
            const int rb = m0 + wm * 64 + m * 16 + lg * 4;
            const float bv = bias[col];
#pragma unroll
            for (int r = 0; r < 4; ++r)
                C[(size_t)(rb + r) * N + col] = acc[m][n][r] + bv;
        }
}

// ---------------------------------------------------------------------------
// Flash attention v6: swapped QK^T; P packed b64 stores; no-max softmax via
// exp2 (Wq pre-scaled); row sums on the MFMA pipe via B=ones.
// grid 1024 blocks (XCD-chunked swizzle), block 256 (4 waves).
__global__ __launch_bounds__(256) void attn_k(const u16* __restrict__ Q,
                                              const u16* __restrict__ Kp,
                                              const u16* __restrict__ VT,
                                              u16* __restrict__ AO) {
    __shared__ __align__(16) u16 Ksm[2][64 * 64];
    __shared__ __align__(16) u16 Vsm[2][64 * 64];
    __shared__ __align__(16) u16 Psm[4][16 * 64];

    const int tid = threadIdx.x, lane = tid & 63, wv = tid >> 6;
    const int lr = lane & 15, lg = lane >> 4;

    const int swz = (blockIdx.x & 7) * 128 + (blockIdx.x >> 3);
    const int bh = swz >> 4;
    const int b = bh >> 4, h = bh & 15;
    const int q0 = (swz & 15) * 64 + wv * 16;
    const int lx = lr & 7;

    bf16x8 qf[2];
#pragma unroll
    for (int ks = 0; ks < 2; ++ks)
        qf[ks] = *(const bf16x8*)&Q[(size_t)(b * NQ + q0 + lr) * HD +
                                    h * 64 + ks * 32 + lg * 8];

    bf16x8 onesf;
#pragma unroll
    for (int i = 0; i < 8; ++i) onesf[i] = (__bf16)1.0f;

    const int kbase = b * NKK, vrow0 = h * 64;
    auto stageKV = [&](int kt, int bufsel) {
#pragma unroll
        for (int i = 0; i < 2; ++i) {
            const int cb = (wv * 2 + i) * 64;
            const int s = cb + lane;
            const int row = s >> 3;
            const int cg = (s & 7) ^ (row & 7);
            GLOAD16(Kp + (size_t)(kbase + kt + row) * HD + h * 64 + cg * 8,
                    &Ksm[bufsel][cb * 8]);
            GLOAD16(VT + (size_t)(vrow0 + row) * (BATCH * NKK) + kbase + kt + cg * 8,
                    &Vsm[bufsel][cb * 8]);
        }
    };

    f32x4 osum = (f32x4)(0.0f);
    f32x4 o[4];
#pragma unroll
    for (int n = 0; n < 4; ++n) o[n] = (f32x4)(0.0f);

    stageKV(0, 0);
    __syncthreads();
    int cur = 0;

    for (int t = 0; t < NKK / 64; ++t) {
        if (t + 1 < NKK / 64) stageKV((t + 1) * 64, cur ^ 1);
        const u16* Ks = &Ksm[cur][0];
        const u16* Vs = &Vsm[cur][0];

        f32x4 s[4];
#pragma unroll
        for (int n = 0; n < 4; ++n) s[n] = (f32x4)(0.0f);
        __builtin_amdgcn_s_setprio(1);
#pragma unroll
        for (int n = 0; n < 4; ++n) {
            bf16x8 kf0 = *(const bf16x8*)&Ks[(n * 16 + lr) * 64 + (lg ^ lx) * 8];
            bf16x8 kf1 = *(const bf16x8*)&Ks[(n * 16 + lr) * 64 + ((lg | 4) ^ lx) * 8];
            s[n] = MFMA16(kf0, qf[0], s[n]);
            s[n] = MFMA16(kf1, qf[1], s[n]);
        }
        __builtin_amdgcn_s_setprio(0);

        u16* P = &Psm[wv][0];
#pragma unroll
        for (int n = 0; n < 4; ++n) {
            const float p0 = exp2f(s[n][0]);
            const float p1 = exp2f(s[n][1]);
            const float p2 = exp2f(s[n][2]);
            const float p3 = exp2f(s[n][3]);
            ushort4 pk;
            pk.x = f2bf(p0); pk.y = f2bf(p1); pk.z = f2bf(p2); pk.w = f2bf(p3);
            const int ch = (2 * n + (lg >> 1)) ^ lx;
            *(ushort4*)&P[lr * 64 + ch * 8 + (lg & 1) * 4] = pk;
        }

#pragma unroll
        for (int ks = 0; ks < 2; ++ks) {
            bf16x8 pa = *(const bf16x8*)&P[lr * 64 + (((ks * 4 + lg) ^ lx)) * 8];
            __builtin_amdgcn_s_setprio(1);
#pragma unroll
            for (int n = 0; n < 4; ++n) {
                bf16x8 vf = *(const bf16x8*)&Vs[(n * 16 + lr) * 64 + (((ks * 4 + lg) ^ lx)) * 8];
                o[n] = MFMA16(pa, vf, o[n]);
            }
            osum = MFMA16(pa, onesf, osum);
            __builtin_amdgcn_s_setprio(0);
        }
        __syncthreads();
        cur ^= 1;
    }

    float rs[4];
#pragma unroll
    for (int r = 0; r < 4; ++r) rs[r] = 1.0f / osum[r];

#pragma unroll
    for (int n = 0; n < 4; ++n)
#pragma unroll
        for (int r = 0; r < 4; ++r) {
            const float val = o[n][r] * rs[r];
            AO[(size_t)(b * NQ + q0 + lg * 4 + r) * HD +
               h * 64 + n * 16 + lr] = f2bf(val);
        }
}

// ---------------------------------------------------------------------------
extern "C" void kernel_launch(void* const* d_in, const int* in_sizes, int n_in,
                              void* d_out, int out_size, void* d_ws, size_t ws_size,
                              hipStream_t stream) {
    const float* x   = (const float*)d_in[0];
    const float* ctx = (const float*)d_in[1];
    const float* Wq  = (const float*)d_in[2];
    const float* Wk  = (const float*)d_in[3];
    const float* Wv  = (const float*)d_in[4];
    const float* Wo  = (const float*)d_in[5];
    const float* bo  = (const float*)d_in[6];

    u16* ws = (u16*)d_ws;
    const size_t MEG = 1024u * 1024u;
    u16* WT3 = ws + 0 * MEG;    // [WqT|WkT|WvT] = [3072][1024]
    u16* WoT = ws + 3 * MEG;
    u16* Xb  = ws + 4 * MEG;
    u16* Cb  = ws + 8 * MEG;
    u16* Qb  = ws + 12 * MEG;
    u16* Kb  = ws + 16 * MEG;
    u16* VTb = ws + 20 * MEG;   // [1024][4096]
    u16* AOb = Xb;              // reuse: x dead after gemm_qkv8

    hipFuncSetAttribute((const void*)gemm_qkv8,
                        hipFuncAttributeMaxDynamicSharedMemorySize, 131072);

    prep_k<<<dim3(16, 16, 6), 256, 0, stream>>>(x, ctx, Wq, Wk, Wv, Wo, ws, Xb, Cb);
    gemm_qkv8<<<192, 512, 131072, stream>>>(Xb, Cb, WT3, Qb, Kb, VTb);
    attn_k<<<1024, 256, 0, stream>>>(Qb, Kb, VTb, AOb);
    gemm_out<<<256, 512, 0, stream>>>(AOb, WoT, bo, (float*)d_out);
}

// Round 20
// 99.515 us; speedup vs baseline: 1.0792x; 1.0792x over previous
//
#include <hip/hip_runtime.h>
#include <hip/hip_bf16.h>

#define BATCH 4
#define NQ 1024
#define NKK 1024
#define HD 1024
#define NHEADS 16

typedef __bf16 bf16x8 __attribute__((ext_vector_type(8)));
typedef float f32x4 __attribute__((ext_vector_type(4)));
typedef unsigned short u16;
typedef unsigned short u16x8 __attribute__((ext_vector_type(8)));
typedef unsigned int u32;

__device__ __forceinline__ u16 f2bf(float f) {
    union { __bf16 h; u16 u; } v;
    v.h = (__bf16)f;           // compiler emits v_cvt_pk_bf16_f32 for pairs
    return v.u;
}

#define GLOAD16(gp, lp) \
    __builtin_amdgcn_global_load_lds((const __attribute__((address_space(1))) void*)(gp), \
                                     (__attribute__((address_space(3))) void*)(lp), 16, 0, 0)

#define MFMA16(a, b, c) __builtin_amdgcn_mfma_f32_16x16x32_bf16(a, b, c, 0, 0, 0)

// ---------------------------------------------------------------------------
// Merged preprocessing, one launch. grid (16,16,6), block 256.
// z=0..3: transpose+convert weight z (Wq pre-scaled by 0.125*log2e) -> ws[z].
// z=4:    convert x  f32 -> bf16.   z=5: convert ctx f32 -> bf16.
__global__ __launch_bounds__(256) void prep_k(const float* __restrict__ x,
                                              const float* __restrict__ ctx,
                                              const float* __restrict__ w0,
                                              const float* __restrict__ w1,
                                              const float* __restrict__ w2,
                                              const float* __restrict__ w3,
                                              u16* __restrict__ ws,
                                              u16* __restrict__ Xb,
                                              u16* __restrict__ Cb) {
    const int tid = threadIdx.x;
    const int z = blockIdx.z;
    if (z >= 4) {
        const float* src = (z == 4) ? x : ctx;
        u16* dst = (z == 4) ? Xb : Cb;
        const int seg = blockIdx.y * 16 + blockIdx.x;   // 0..255
#pragma unroll
        for (int p = 0; p < 16; ++p) {
            const int i = seg * 4096 + p * 256 + tid;   // float4 index, < 1M
            float4 v = ((const float4*)src)[i];
            ushort4 pk;
            pk.x = f2bf(v.x); pk.y = f2bf(v.y); pk.z = f2bf(v.z); pk.w = f2bf(v.w);
            ((ushort4*)dst)[i] = pk;
        }
        return;
    }
    const float* src = z == 0 ? w0 : z == 1 ? w1 : z == 2 ? w2 : w3;
    const float scl = (z == 0) ? 0.18033688011112042f : 1.0f;  // 0.125*log2e
    u16* dst = ws + (size_t)z * (1024u * 1024u);
    __shared__ u16 t[64][65];
    const int bx = blockIdx.x * 64;
    const int by = blockIdx.y * 64;
#pragma unroll
    for (int p = 0; p < 16; ++p) {
        int idx = p * 256 + tid;
        int r = idx >> 6, c = idx & 63;
        t[c][r] = f2bf(scl * src[(size_t)(by + r) * 1024 + bx + c]);
    }
    __syncthreads();
#pragma unroll
    for (int p = 0; p < 16; ++p) {
        int idx = p * 256 + tid;
        int r = idx >> 6, c = idx & 63;
        dst[(size_t)(bx + r) * 1024 + by + c] = t[r][c];
    }
}

// ---------------------------------------------------------------------------
// Fused QKV projection. 128x128 tiles, 8 waves (512 thr), BK=64, swizzled LDS.
// grid 768 (8 XCD x 96, bijective), 3 blocks/CU x 8 waves = 24 waves/CU.
// Wave (wm,wn) = (wv>>2, wv&3) owns a 64x32 output sub-tile.
__global__ __launch_bounds__(512) void gemm_qkv(const u16* __restrict__ Xb,
                                                const u16* __restrict__ Cb,
                                                const u16* __restrict__ WqT,
                                                const u16* __restrict__ WkT,
                                                const u16* __restrict__ WvT,
                                                u16* __restrict__ Qb,
                                                u16* __restrict__ Kb,
                                                u16* __restrict__ VTb) {
    const int bid = blockIdx.x;
    const int swz = (bid & 7) * 96 + (bid >> 3);    // bijective on [0,768)
    const int z = swz >> 8;                         // 0..2
    const int rem = swz & 255;
    const int m0 = (rem >> 3) * 128;                // <= 3968
    const int n0 = (rem & 7) * 128;                 // <= 896

    const u16* __restrict__ A  = (z == 0) ? Xb : Cb;
    const u16* __restrict__ BT = (z == 0) ? WqT : (z == 1) ? WkT : WvT;

    __shared__ __align__(16) u16 Asm[128 * 64];   // 8 chunks/row, swizzled
    __shared__ __align__(16) u16 Bsm[128 * 64];

    const int tid = threadIdx.x, lane = tid & 63, wv = tid >> 6;
    const int wm = wv >> 2, wn = wv & 3;    // wave: rows wm*64.., cols wn*32..
    const int lr = lane & 15, lg = lane >> 4;
    const int lx = lr & 7;
    const int M = BATCH * NQ, N = HD, K = HD;

    f32x4 acc[4][2];
#pragma unroll
    for (int i = 0; i < 4; ++i)
#pragma unroll
        for (int j = 0; j < 2; ++j) acc[i][j] = (f32x4)(0.0f);

    for (int kt = 0; kt < K; kt += 64) {
        __syncthreads();
        // A,B: 1024 16B-chunks each; 2 per thread each
#pragma unroll
        for (int i = 0; i < 2; ++i) {
            const int cb = (wv * 2 + i) * 64;
            const int s = cb + lane;
            const int row = s >> 3, cg = (s & 7) ^ (row & 7);
            GLOAD16(A + (size_t)(m0 + row) * K + kt + cg * 8, &Asm[cb * 8]);
            GLOAD16(BT + (size_t)(n0 + row) * K + kt + cg * 8, &Bsm[cb * 8]);
        }
        __syncthreads();
        bf16x8 af[4][2], bfr[2][2];
#pragma unroll
        for (int m = 0; m < 4; ++m)
#pragma unroll
            for (int kk = 0; kk < 2; ++kk)
                af[m][kk] = *(const bf16x8*)&Asm[((wm * 64 + m * 16 + lr) * 8 +
                                                 ((kk * 4 + lg) ^ lx)) * 8];
#pragma unroll
        for (int n = 0; n < 2; ++n)
#pragma unroll
            for (int kk = 0; kk < 2; ++kk)
                bfr[n][kk] = *(const bf16x8*)&Bsm[((wn * 32 + n * 16 + lr) * 8 +
                                                  ((kk * 4 + lg) ^ lx)) * 8];
#pragma unroll
        for (int kk = 0; kk < 2; ++kk)
#pragma unroll
            for (int m = 0; m < 4; ++m)
#pragma unroll
                for (int n = 0; n < 2; ++n)
                    acc[m][n] = MFMA16(af[m][kk], bfr[n][kk], acc[m][n]);
    }

    if (z < 2) {
        u16* __restrict__ C = (z == 0) ? Qb : Kb;
#pragma unroll
        for (int m = 0; m < 4; ++m)
#pragma unroll
            for (int n = 0; n < 2; ++n) {
                const int col = n0 + wn * 32 + n * 16 + lr;
                const int rb = m0 + wm * 64 + m * 16 + lg * 4;
#pragma unroll
                for (int r = 0; r < 4; ++r)
                    C[(size_t)(rb + r) * N + col] = f2bf(acc[m][n][r]);
            }
    } else {
        // transposed store: VT[col][m], row stride M; 4 consecutive m -> 8B store
#pragma unroll
        for (int m = 0; m < 4; ++m)
#pragma unroll
            for (int n = 0; n < 2; ++n) {
                const int col = n0 + wn * 32 + n * 16 + lr;
                const int rb = m0 + wm * 64 + m * 16 + lg * 4;
                ushort4 pk;
                pk.x = f2bf(acc[m][n][0]);
                pk.y = f2bf(acc[m][n][1]);
                pk.z = f2bf(acc[m][n][2]);
                pk.w = f2bf(acc[m][n][3]);
                *(ushort4*)&VTb[(size_t)col * M + rb] = pk;
            }
    }
}

// ---------------------------------------------------------------------------
// Output projection with f32 bias: out = AO @ Wo + bo -> f32.
// 128x128 tiles, 8 waves, BK=64, swizzled LDS. grid 256 (= 8 XCD x 32).
__global__ __launch_bounds__(512) void gemm_out(const u16* __restrict__ A,
                                                const u16* __restrict__ BT,
                                                const float* __restrict__ bias,
                                                float* __restrict__ C) {
    const int bid = blockIdx.x;
    const int swz = (bid & 7) * 32 + (bid >> 3);    // bijective on [0,256)
    const int m0 = (swz >> 3) * 128;                // <= 3968
    const int n0 = (swz & 7) * 128;                 // <= 896

    __shared__ __align__(16) u16 Asm[128 * 64];
    __shared__ __align__(16) u16 Bsm[128 * 64];

    const int tid = threadIdx.x, lane = tid & 63, wv = tid >> 6;
    const int wm = wv >> 2, wn = wv & 3;
    const int lr = lane & 15, lg = lane >> 4;
    const int lx = lr & 7;
    const int N = HD, K = HD;

    f32x4 acc[4][2];
#pragma unroll
    for (int i = 0; i < 4; ++i)
#pragma unroll
        for (int j = 0; j < 2; ++j) acc[i][j] = (f32x4)(0.0f);

    for (int kt = 0; kt < K; kt += 64) {
        __syncthreads();
#pragma unroll
        for (int i = 0; i < 2; ++i) {
            const int cb = (wv * 2 + i) * 64;
            const int s = cb + lane;
            const int row = s >> 3, cg = (s & 7) ^ (row & 7);
            GLOAD16(A + (size_t)(m0 + row) * K + kt + cg * 8, &Asm[cb * 8]);
            GLOAD16(BT + (size_t)(n0 + row) * K + kt + cg * 8, &Bsm[cb * 8]);
        }
        __syncthreads();
        bf16x8 af[4][2], bfr[2][2];
#pragma unroll
        for (int m = 0; m < 4; ++m)
#pragma unroll
            for (int kk = 0; kk < 2; ++kk)
                af[m][kk] = *(const bf16x8*)&Asm[((wm * 64 + m * 16 + lr) * 8 +
                                                 ((kk * 4 + lg) ^ lx)) * 8];
#pragma unroll
        for (int n = 0; n < 2; ++n)
#pragma unroll
            for (int kk = 0; kk < 2; ++kk)
                bfr[n][kk] = *(const bf16x8*)&Bsm[((wn * 32 + n * 16 + lr) * 8 +
                                                  ((kk * 4 + lg) ^ lx)) * 8];
#pragma unroll
        for (int kk = 0; kk < 2; ++kk)
#pragma unroll
            for (int m = 0; m < 4; ++m)
#pragma unroll
                for (int n = 0; n < 2; ++n)
                    acc[m][n] = MFMA16(af[m][kk], bfr[n][kk], acc[m][n]);
    }

#pragma unroll
    for (int m = 0; m < 4; ++m)
#pragma unroll
        for (int n = 0; n < 2; ++n) {
            const int col = n0 + wn * 32 + n * 16 + lr;
            const int rb = m0 + wm * 64 + m * 16 + lg * 4;
            const float bv = bias[col];
#pragma unroll
            for (int r = 0; r < 4; ++r)
                C[(size_t)(rb + r) * N + col] = acc[m][n][r] + bv;
        }
}

// ---------------------------------------------------------------------------
// Flash attention v6: swapped QK^T (S^T = mfma(K,Q)); P packed b64 stores;
// no-max softmax via exp2 (Wq pre-scaled); row sums on the MFMA pipe (B=ones,
// C-frag lands sums at exactly the stored rows q = lg*4+r).
// grid 1024 blocks (XCD-chunked swizzle), block 256 (4 waves).
__global__ __launch_bounds__(256) void attn_k(const u16* __restrict__ Q,
                                              const u16* __restrict__ Kp,
                                              const u16* __restrict__ VT,
                                              u16* __restrict__ AO) {
    __shared__ __align__(16) u16 Ksm[2][64 * 64];   // K[kk][d], swizzled
    __shared__ __align__(16) u16 Vsm[2][64 * 64];   // V^T[d][kk], swizzled
    __shared__ __align__(16) u16 Psm[4][16 * 64];   // per-wave P[q][kk], swizzled

    const int tid = threadIdx.x, lane = tid & 63, wv = tid >> 6;
    const int lr = lane & 15, lg = lane >> 4;

    const int swz = (blockIdx.x & 7) * 128 + (blockIdx.x >> 3);
    const int bh = swz >> 4;             // 0..63 combined (b,h)
    const int b = bh >> 4, h = bh & 15;
    const int q0 = (swz & 15) * 64 + wv * 16;
    const int lx = lr & 7;

    bf16x8 qf[2];
#pragma unroll
    for (int ks = 0; ks < 2; ++ks)
        qf[ks] = *(const bf16x8*)&Q[(size_t)(b * NQ + q0 + lr) * HD +
                                    h * 64 + ks * 32 + lg * 8];

    bf16x8 onesf;
#pragma unroll
    for (int i = 0; i < 8; ++i) onesf[i] = (__bf16)1.0f;

    const int kbase = b * NKK, vrow0 = h * 64;
    auto stageKV = [&](int kt, int bufsel) {
#pragma unroll
        for (int i = 0; i < 2; ++i) {
            const int cb = (wv * 2 + i) * 64;
            const int s = cb + lane;
            const int row = s >> 3;
            const int cg = (s & 7) ^ (row & 7);
            GLOAD16(Kp + (size_t)(kbase + kt + row) * HD + h * 64 + cg * 8,
                    &Ksm[bufsel][cb * 8]);
            GLOAD16(VT + (size_t)(vrow0 + row) * (BATCH * NKK) + kbase + kt + cg * 8,
                    &Vsm[bufsel][cb * 8]);
        }
    };

    f32x4 osum = (f32x4)(0.0f);    // row sums via ones-MFMA (q = lg*4+r)
    f32x4 o[4];
#pragma unroll
    for (int n = 0; n < 4; ++n) o[n] = (f32x4)(0.0f);

    stageKV(0, 0);
    __syncthreads();
    int cur = 0;

    for (int t = 0; t < NKK / 64; ++t) {
        if (t + 1 < NKK / 64) stageKV((t + 1) * 64, cur ^ 1);
        const u16* Ks = &Ksm[cur][0];
        const u16* Vs = &Vsm[cur][0];

        // swapped QK^T: s[n] = S^T subtile; lane holds q=lr, k=n*16+lg*4+r.
        f32x4 s[4];
#pragma unroll
        for (int n = 0; n < 4; ++n) s[n] = (f32x4)(0.0f);
        __builtin_amdgcn_s_setprio(1);
#pragma unroll
        for (int n = 0; n < 4; ++n) {
            bf16x8 kf0 = *(const bf16x8*)&Ks[(n * 16 + lr) * 64 + (lg ^ lx) * 8];
            bf16x8 kf1 = *(const bf16x8*)&Ks[(n * 16 + lr) * 64 + ((lg | 4) ^ lx) * 8];
            s[n] = MFMA16(kf0, qf[0], s[n]);
            s[n] = MFMA16(kf1, qf[1], s[n]);
        }
        __builtin_amdgcn_s_setprio(0);

        // P = exp2(S); pack 4 consecutive k (r=0..3) into one b64 store.
        u16* P = &Psm[wv][0];
#pragma unroll
        for (int n = 0; n < 4; ++n) {
            const float p0 = exp2f(s[n][0]);
            const float p1 = exp2f(s[n][1]);
            const float p2 = exp2f(s[n][2]);
            const float p3 = exp2f(s[n][3]);
            ushort4 pk;
            pk.x = f2bf(p0); pk.y = f2bf(p1); pk.z = f2bf(p2); pk.w = f2bf(p3);
            const int ch = (2 * n + (lg >> 1)) ^ lx;
            *(ushort4*)&P[lr * 64 + ch * 8 + (lg & 1) * 4] = pk;
        }

        // PV: o += P @ V; row-sums via B=ones on the MFMA pipe.
#pragma unroll
        for (int ks = 0; ks < 2; ++ks) {
            bf16x8 pa = *(const bf16x8*)&P[lr * 64 + (((ks * 4 + lg) ^ lx)) * 8];
            __builtin_amdgcn_s_setprio(1);
#pragma unroll
            for (int n = 0; n < 4; ++n) {
                bf16x8 vf = *(const bf16x8*)&Vs[(n * 16 + lr) * 64 + (((ks * 4 + lg) ^ lx)) * 8];
                o[n] = MFMA16(pa, vf, o[n]);
            }
            osum = MFMA16(pa, onesf, osum);
            __builtin_amdgcn_s_setprio(0);
        }
        __syncthreads();
        cur ^= 1;
    }

    // normalize + store (osum[r] is the row sum for q = lg*4+r)
    float rs[4];
#pragma unroll
    for (int r = 0; r < 4; ++r) rs[r] = 1.0f / osum[r];

#pragma unroll
    for (int n = 0; n < 4; ++n)
#pragma unroll
        for (int r = 0; r < 4; ++r) {
            const float val = o[n][r] * rs[r];
            AO[(size_t)(b * NQ + q0 + lg * 4 + r) * HD +
               h * 64 + n * 16 + lr] = f2bf(val);
        }
}

// ---------------------------------------------------------------------------
extern "C" void kernel_launch(void* const* d_in, const int* in_sizes, int n_in,
                              void* d_out, int out_size, void* d_ws, size_t ws_size,
                              hipStream_t stream) {
    const float* x   = (const float*)d_in[0];
    const float* ctx = (const float*)d_in[1];
    const float* Wq  = (const float*)d_in[2];
    const float* Wk  = (const float*)d_in[3];
    const float* Wv  = (const float*)d_in[4];
    const float* Wo  = (const float*)d_in[5];
    const float* bo  = (const float*)d_in[6];

    u16* ws = (u16*)d_ws;
    const size_t MEG = 1024u * 1024u;
    u16* WqT = ws + 0 * MEG;
    u16* WkT = ws + 1 * MEG;
    u16* WvT = ws + 2 * MEG;
    u16* WoT = ws + 3 * MEG;
    u16* Xb  = ws + 4 * MEG;    // bf16 x        [4096][1024]
    u16* Cb  = ws + 8 * MEG;    // bf16 context  [4096][1024]
    u16* Qb  = ws + 12 * MEG;   // [4096][1024]
    u16* Kb  = ws + 16 * MEG;   // [4096][1024]
    u16* VTb = ws + 20 * MEG;   // [1024][4096]
    u16* AOb = Xb;              // reuse: x dead after gemm_qkv

    prep_k<<<dim3(16, 16, 6), 256, 0, stream>>>(x, ctx, Wq, Wk, Wv, Wo, ws, Xb, Cb);
    gemm_qkv<<<768, 512, 0, stream>>>(Xb, Cb, WqT, WkT, WvT, Qb, Kb, VTb);
    attn_k<<<1024, 256, 0, stream>>>(Qb, Kb, VTb, AOb);
    gemm_out<<<256, 512, 0, stream>>>(AOb, WoT, bo, (float*)d_out);
}